// Round 3
// baseline (741.706 us; speedup 1.0000x reference)
//
#include <hip/hip_runtime.h>

// Sobel3D fused (fp32): gx, gy, gz (depthwise separable 3x3x3) in one pass.
//
// R3: pure-SSA f4 vector form — no arrays, no lambda out-pointer arrays.
// R2 post-mortem: pipelining (R1), NT stores (R1), occupancy 2->4 (R2) ALL
// neutral (729.7 / 741.1 / 737.3). Resource accounting: VALU ~21us, DS ~14us,
// L1 ~30us, L2 ~35us, HBM ~130-150us -- nothing explains a ~350us kernel.
// Last untested mechanism: hidden scratch traffic from float[4] arrays passed
// through lambda pointers (rule-#20 class; insensitive to all prior levers).
// This version makes scratch impossible: every value is a named f4 register.
// If neutral again, the kernel is at its compulsory-traffic floor and the
// residual dur_us is harness-fixed (2.25 GiB poison fill @385us = measured
// 6.3 TB/s ceiling + dozens of memset nodes).
//
// Decomposition (XLA conv = cross-correlation, no kernel flip):
//   per plane z: A = S_h*D_w, B = D_h*S_w, C = S_h*S_w   (2D combos)
//   gx[d] = A(d-1) + 2A(d) + A(d+1)
//   gy[d] = B(d-1) + 2B(d) + B(d+1)
//   gz[d] = C(d+1) - C(d-1)
// Thread: 4 consecutive w (float4, 16B I/O), rolls along d. w-halo via wave
// shuffles (edge lanes are the zero-pad boundary), h-halo via direct loads
// (cache-served), d-halo via rolling registers.

#define DDIM 96
#define HDIM 128
#define WDIM 128
#define NCIMG 32                                   // N*C = 2*16
#define NTOTI 50331648                             // elements per output tensor
#define DCHUNK 24
#define PLANE (HDIM * WDIM)                        // 16384 = 1<<14

typedef float f4 __attribute__((ext_vector_type(4)));

__global__ __launch_bounds__(256, 4)
void sobel3d_fused(const float* __restrict__ x, float* __restrict__ out) {
  const int wx = threadIdx.x;            // 0..31 (w-chunk within row)
  const int w0 = wx << 2;                // 0,4,...,124
  const int h  = blockIdx.y * 8 + threadIdx.y;
  const int nc = blockIdx.z >> 2;        // image index 0..31
  const int d0 = (blockIdx.z & 3) * DCHUNK;

  const float* img = x + (size_t)nc * (DDIM * PLANE);

  // h-halo: clamped row offsets + zero-pad scale. s is uniform across the 32
  // lanes of a row, so scaling before the shuffle is equivalent; the lane
  // 31<->32 cross-row shuffle leakage is exactly the wx==0/31 zeroed lanes.
  const int   om = ((h > 0 ? h - 1 : 0) << 7) + w0;
  const int   o0 = (h << 7) + w0;
  const int   op = ((h < HDIM - 1 ? h + 1 : h) << 7) + w0;
  const float sm = (h > 0) ? 1.f : 0.f;
  const float sp = (h < HDIM - 1) ? 1.f : 0.f;

  // Issue the 3 row loads of plane z (pure issue; no wait until use).
  auto loadPlane = [&](int z, f4& vm, f4& v0, f4& vp) {
    const int zb = z << 14;
    vm = *(const f4*)(img + zb + om);
    v0 = *(const f4*)(img + zb + o0);
    vp = *(const f4*)(img + zb + op);
  };

  // Row smooth (P = S_w) and derivative (Q = D_w), all named f4 registers.
  auto rowPQ = [&](f4 v, float s, f4& P, f4& Q) {
    v *= s;
    float xm = __shfl_up(v.w, 1);        // left neighbor's elem 3  (w0-1)
    float xp = __shfl_down(v.x, 1);      // right neighbor's elem 0 (w0+4)
    if (wx == 0)  xm = 0.f;              // w = -1  -> zero pad
    if (wx == 31) xp = 0.f;              // w = 128 -> zero pad
    const f4 vL = {xm, v.x, v.y, v.z};
    const f4 vR = {v.y, v.z, v.w, xp};
    P = vL + 2.f * v + vR;
    Q = vR - vL;
  };

  // 2D combos of one plane from its 3 raw rows (registers in, registers out).
  auto combos = [&](f4 vm, f4 v0, f4 vp, f4& A, f4& B, f4& C) {
    f4 Pm, Qm, P0, Q0, Pp, Qp;
    rowPQ(vm, sm, Pm, Qm);
    rowPQ(v0, 1.f, P0, Q0);
    rowPQ(vp, sp, Pp, Qp);
    A = Qm + 2.f * Q0 + Qp;              // S_h * D_w
    B = Pp - Pm;                         // D_h * S_w
    C = Pm + 2.f * P0 + Pp;              // S_h * S_w
  };

  f4 A0, B0, C0, A1, B1, C1;             // combos of planes d-1, d
  f4 rm, r0, rp;                         // raw rows of plane d+1 (pipelined)

  // Prime: combos for planes d0-1 (zero if OOB) and d0; raw rows for d0+1.
  {
    const int zm = d0 - 1;
    f4 a, b, c;
    loadPlane(zm < 0 ? 0 : zm, a, b, c);
    combos(a, b, c, A0, B0, C0);
    if (zm < 0) { A0 = 0.f; B0 = 0.f; C0 = 0.f; }
  }
  {
    f4 a, b, c;
    loadPlane(d0, a, b, c);
    combos(a, b, c, A1, B1, C1);
  }
  loadPlane(d0 + 1, rm, r0, rp);         // d0+1 <= 73 < 96: always in range

  int o = ((nc * DDIM + d0) * HDIM + h) * WDIM + w0;  // max ~50M, fits int

#pragma unroll 2
  for (int d = d0; d < d0 + DCHUNK; ++d) {
    // 1) ISSUE loads for plane d+2 (consumed next iteration).
    f4 nm, n0, np;
    const int zn = d + 2;
    loadPlane(zn >= DDIM ? DDIM - 1 : zn, nm, n0, np);

    // 2) Combos for plane d+1 from registers loaded last iteration.
    f4 A2, B2, C2;
    combos(rm, r0, rp, A2, B2, C2);
    if (d + 1 >= DDIM) { A2 = 0.f; B2 = 0.f; C2 = 0.f; }  // last iter only

    // 3) Combine along d and store (nontemporal: write-once, never re-read).
    const f4 gx = A0 + 2.f * A1 + A2;
    const f4 gy = B0 + 2.f * B1 + B2;
    const f4 gz = C2 - C0;
    __builtin_nontemporal_store(gx, (f4*)(out + o));
    __builtin_nontemporal_store(gy, (f4*)(out + NTOTI + o));
    __builtin_nontemporal_store(gz, (f4*)(out + 2 * NTOTI + o));
    o += PLANE;

    // 4) Roll state (pure register renames under unroll).
    A0 = A1; B0 = B1; C0 = C1;
    A1 = A2; B1 = B2; C1 = C2;
    rm = nm; r0 = n0; rp = np;
  }
}

extern "C" void kernel_launch(void* const* d_in, const int* in_sizes, int n_in,
                              void* d_out, int out_size, void* d_ws, size_t ws_size,
                              hipStream_t stream) {
  const float* x = (const float*)d_in[0];
  float* out = (float*)d_out;
  dim3 block(32, 8, 1);
  dim3 grid(1, HDIM / 8, NCIMG * (DDIM / DCHUNK));  // (1, 16, 128)
  hipLaunchKernelGGL(sobel3d_fused, grid, block, 0, stream, x, out);
}